// Round 7
// baseline (1607.130 us; speedup 1.0000x reference)
//
#include <hip/hip_runtime.h>
#include <hip/hip_fp16.h>
#include <hip/hip_cooperative_groups.h>

namespace cg = cooperative_groups;

#define N_NODES_C 100000
#define N_EDGES_C 1600000
#define N_GRAPHS_C 2000
#define HID 128
#define BN_EPS_C 1e-5f
#define NBUCK 391          // ceil(100000 / 256) buckets of 256 nodes
#define PART_TILE 4096
#define PB_C 391           // edge chunks (ceil 1.6M/4096)
#define GB_C 782           // gemm tiles of 128 nodes
#define AB_C 25000         // agg groups of 4 nodes
#define PU_C 3125          // pool units of 32 nodes

typedef _Float16 half8 __attribute__((ext_vector_type(8)));
typedef float float4v __attribute__((ext_vector_type(4)));

// ---- workspace layout (256B-aligned constexpr offsets) ----
constexpr size_t al(size_t v) { return (v + 255) & ~(size_t)255; }
constexpr size_t OFF_H    = 0;
constexpr size_t OFF_Y    = al(OFF_H    + (size_t)N_NODES_C * HID * 2);
constexpr size_t OFF_WT   = al(OFF_Y    + (size_t)(N_NODES_C + 128) * HID * 2);
constexpr size_t OFF_CSR  = al(OFF_WT   + (size_t)4 * HID * HID * 2);
constexpr size_t OFF_OFFS = al(OFF_CSR  + (size_t)(N_EDGES_C + 16) * 4);
constexpr size_t OFF_NORM = al(OFF_OFFS + (size_t)(N_NODES_C + 1) * 4);
constexpr size_t OFF_BB   = al(OFF_NORM + (size_t)N_NODES_C * 4);
constexpr size_t OFF_BCUR = al(OFF_BB   + (NBUCK + 1) * 4);
constexpr size_t OFF_ZERO = al(OFF_BCUR + (NBUCK + 1) * 4);   // zero-group start
constexpr size_t OFF_PSUM = OFF_ZERO;
constexpr size_t OFF_PCNT = al(OFF_PSUM + (size_t)N_GRAPHS_C * HID * 4);
constexpr size_t OFF_BCNT = al(OFF_PCNT + (size_t)N_GRAPHS_C * 4);
constexpr size_t OFF_END  = al(OFF_BCNT + (NBUCK + 1) * 4);

union SM {
    _Float16 Wt[HID][136];                                   // 34816 B (gemm staging)
    struct { int hist[NBUCK], startA[NBUCK], lcur[NBUCK]; } part;
    struct { int s[256], excl[256], lcur[256]; } fill;
    int scan[512];
    float red[2][128][5];
};

__global__ __launch_bounds__(256, 4) void k_mega(
    const float* __restrict__ x, const int* __restrict__ eidx, const int* __restrict__ batch,
    const float* __restrict__ Ws_all, const float* __restrict__ bs, const float* __restrict__ gammas,
    const float* __restrict__ betas, const float* __restrict__ run_mean, const float* __restrict__ run_var,
    const float* __restrict__ W_out, const float* __restrict__ b_out, float* __restrict__ out,
    char* __restrict__ ws)
{
    __shared__ SM sm;
    cg::grid_group grid = cg::this_grid();
    const int tid = threadIdx.x, bid = blockIdx.x, G = gridDim.x;
    const int* src = eidx;
    const int* dst = eidx + N_EDGES_C;

    __half*   h      = (__half*)(ws + OFF_H);
    _Float16* y      = (_Float16*)(ws + OFF_Y);
    int*      ebuf   = (int*)(ws + OFF_Y);       // alias: packed edges, dead before first gemm writes y
    _Float16* WT     = (_Float16*)(ws + OFF_WT);
    int*      csr    = (int*)(ws + OFF_CSR);
    int*      offs   = (int*)(ws + OFF_OFFS);
    float*    norm   = (float*)(ws + OFF_NORM);
    int*      bbase  = (int*)(ws + OFF_BB);
    int*      bcur   = (int*)(ws + OFF_BCUR);
    float*    psum   = (float*)(ws + OFF_PSUM);
    int*      pcount = (int*)(ws + OFF_PCNT);
    int*      bcount = (int*)(ws + OFF_BCNT);

    // ---------- phase Z: zero psum/pcount/bcount + transpose W ----------
    {
        int* zp = (int*)(ws + OFF_ZERO);
        const int zn = (int)((OFF_END - OFF_ZERO) >> 2);
        for (int i = bid * 256 + tid; i < zn; i += G * 256) zp[i] = 0;
        for (int i = bid * 256 + tid; i < 4 * HID * HID; i += G * 256) {
            int l = i >> 14, r = i & 16383, k = r >> 7, n = r & 127;
            WT[l * 16384 + n * HID + k] = (_Float16)Ws_all[i];
        }
    }
    grid.sync();

    // ---------- phase H: histogram of dst buckets ----------
    for (int c = bid; c < PB_C; c += G) {
        for (int b = tid; b < NBUCK; b += 256) sm.part.hist[b] = 0;
        __syncthreads();
        const int e0 = c * PART_TILE;
        #pragma unroll
        for (int k = 0; k < 16; k++) {
            int e = e0 + k * 256 + tid;
            if (e < N_EDGES_C) atomicAdd(&sm.part.hist[dst[e] >> 8], 1);
        }
        __syncthreads();
        for (int b = tid; b < NBUCK; b += 256) {
            int cc = sm.part.hist[b];
            if (cc) atomicAdd(&bcount[b], cc);
        }
        __syncthreads();
    }
    grid.sync();

    // ---------- phase S: scan of bucket counts (block 0, 2 slots/thread) ----------
    if (bid == 0) {
        int v0 = (tid < NBUCK) ? bcount[tid] : 0;
        int v1 = (tid + 256 < NBUCK) ? bcount[tid + 256] : 0;
        sm.scan[tid] = v0; sm.scan[tid + 256] = v1;
        __syncthreads();
        for (int off = 1; off < 512; off <<= 1) {
            int a = (tid >= off) ? sm.scan[tid - off] : 0;
            int b = (tid + 256 >= off) ? sm.scan[tid + 256 - off] : 0;
            __syncthreads();
            sm.scan[tid] += a; sm.scan[tid + 256] += b;
            __syncthreads();
        }
        if (tid < NBUCK) { int e = sm.scan[tid] - v0; bbase[tid] = e; bcur[tid] = e; }
        if (tid + 256 < NBUCK) { int e = sm.scan[tid + 256] - v1; bbase[tid + 256] = e; bcur[tid + 256] = e; }
        if (tid == 0) bbase[NBUCK] = N_EDGES_C;
    }
    grid.sync();

    // ---------- phase P: partition edges into bucket regions (packed 4B) ----------
    for (int c = bid; c < PB_C; c += G) {
        for (int b = tid; b < NBUCK; b += 256) { sm.part.hist[b] = 0; sm.part.lcur[b] = 0; }
        __syncthreads();
        const int e0 = c * PART_TILE;
        #pragma unroll
        for (int k = 0; k < 16; k++) {
            int e = e0 + k * 256 + tid;
            if (e < N_EDGES_C) atomicAdd(&sm.part.hist[dst[e] >> 8], 1);
        }
        __syncthreads();
        for (int b = tid; b < NBUCK; b += 256) {
            int cc = sm.part.hist[b];
            sm.part.startA[b] = cc ? atomicAdd(&bcur[b], cc) : 0;
        }
        __syncthreads();
        #pragma unroll
        for (int k = 0; k < 16; k++) {
            int e = e0 + k * 256 + tid;
            if (e < N_EDGES_C) {
                int d = dst[e];
                int b = d >> 8;
                int pos = sm.part.startA[b] + atomicAdd(&sm.part.lcur[b], 1);
                ebuf[pos] = (src[e] << 8) | (d & 255);
            }
        }
        __syncthreads();
    }
    grid.sync();

    // ---------- phase F: per-bucket local sort -> csr_src, offs, norm ----------
    for (int b = bid; b < NBUCK; b += G) {
        const int base = b << 8;
        const int e0 = bbase[b], e1 = bbase[b + 1];
        sm.fill.s[tid] = 0; sm.fill.lcur[tid] = 0;
        __syncthreads();
        for (int e = e0 + tid; e < e1; e += 256)
            atomicAdd(&sm.fill.s[ebuf[e] & 255], 1);
        __syncthreads();
        int own = sm.fill.s[tid];
        for (int off = 1; off < 256; off <<= 1) {
            int v = (tid >= off) ? sm.fill.s[tid - off] : 0;
            __syncthreads();
            sm.fill.s[tid] += v;
            __syncthreads();
        }
        sm.fill.excl[tid] = sm.fill.s[tid] - own;
        int node = base + tid;
        if (node < N_NODES_C) {
            offs[node] = e0 + sm.fill.excl[tid];
            norm[node] = rsqrtf((float)own + 1.0f);
        }
        if (b == 0 && tid == 0) offs[N_NODES_C] = N_EDGES_C;
        __syncthreads();
        for (int e = e0 + tid; e < e1; e += 256) {
            int p = ebuf[e];
            int l = p & 255;
            int pos = e0 + sm.fill.excl[l] + atomicAdd(&sm.fill.lcur[l], 1);
            csr[pos] = p >> 8;
        }
        __syncthreads();
    }
    grid.sync();

    // ---------- 4 x (GEMM ; sync ; AGG ; sync) ----------
    const int wv = __builtin_amdgcn_readfirstlane(tid >> 6);
    const int lane = tid & 63, quad = lane >> 4, l16 = lane & 15;
    const int j = lane * 2;
    const __half* yh = (const __half*)y;

    for (int l = 0; l < 4; ++l) {
        // -- GEMM: stage W^T once per layer, then grid-stride tiles --
        const _Float16* WTl = WT + (size_t)l * 16384;
        #pragma unroll
        for (int t = 0; t < 8; t++) {
            int off = tid * 8 + t * 2048;
            *(half8*)&sm.Wt[off >> 7][off & 127] = *(const half8*)&WTl[off];
        }
        __syncthreads();
        half8 Wf[2][4];
        #pragma unroll
        for (int c = 0; c < 2; c++)
            #pragma unroll
            for (int ks = 0; ks < 4; ks++)
                Wf[c][ks] = *(const half8*)&sm.Wt[(wv * 2 + c) * 16 + l16][ks * 32 + quad * 8];

        for (int tile = bid; tile < GB_C; tile += G) {
            const int nbase = tile * 128;
            #pragma unroll
            for (int t = 0; t < 8; t++) {
                int node = nbase + t * 16 + l16;
                bool ok = node < N_NODES_C;
                half8 Af[4];
                if (l == 0) {
                    const float* arow = x + (long)node * HID;
                    #pragma unroll
                    for (int ks = 0; ks < 4; ks++) {
                        if (ok) {
                            float4 fa = *(const float4*)&arow[ks * 32 + quad * 8];
                            float4 fb = *(const float4*)&arow[ks * 32 + quad * 8 + 4];
                            _Float16 pk[8] = {(_Float16)fa.x, (_Float16)fa.y, (_Float16)fa.z, (_Float16)fa.w,
                                              (_Float16)fb.x, (_Float16)fb.y, (_Float16)fb.z, (_Float16)fb.w};
                            Af[ks] = *(half8*)pk;
                        } else Af[ks] = half8{};
                    }
                } else {
                    const _Float16* arow = (const _Float16*)h + (long)node * HID;
                    #pragma unroll
                    for (int ks = 0; ks < 4; ks++)
                        Af[ks] = ok ? *(const half8*)&arow[ks * 32 + quad * 8] : half8{};
                }
                float4v a0 = {0.f, 0.f, 0.f, 0.f}, a1 = {0.f, 0.f, 0.f, 0.f};
                #pragma unroll
                for (int ks = 0; ks < 4; ks++) {
                    a0 = __builtin_amdgcn_mfma_f32_16x16x32_f16(Wf[0][ks], Af[ks], a0, 0, 0, 0);
                    a1 = __builtin_amdgcn_mfma_f32_16x16x32_f16(Wf[1][ks], Af[ks], a1, 0, 0, 0);
                }
                float nv = ok ? norm[node] : 0.f;   // pad rows (incl. dummy row N_NODES) -> zeros
                _Float16 p0[4], p1[4];
                #pragma unroll
                for (int r = 0; r < 4; r++) {
                    p0[r] = (_Float16)(a0[r] * nv);
                    p1[r] = (_Float16)(a1[r] * nv);
                }
                *(ushort4*)&y[(long)node * HID + (wv * 2 + 0) * 16 + quad * 4] = *(ushort4*)p0;
                *(ushort4*)&y[(long)node * HID + (wv * 2 + 1) * 16 + quad * 4] = *(ushort4*)p1;
            }
        }
        grid.sync();

        // -- AGG (r3 body): wave per node, scalar indices, padded 16-chains --
        const float* bias = bs + l * HID;
        const float* mean = run_mean + l * HID;
        const float* gam  = gammas + l * HID;
        const float* varr = run_var + l * HID;
        const float* bet  = betas + l * HID;
        for (int grp = bid; grp < AB_C; grp += G) {
            const int i = grp * 4 + wv;
            float2 f = __half22float2(*(const __half2*)&yh[(long)i * HID + j]);
            float acc0 = f.x, acc1 = f.y;
            const int e0 = offs[i], e1 = offs[i + 1];
            int e = e0;
            do {
                int id[16];
                #pragma unroll
                for (int u = 0; u < 16; u++) {
                    int raw = csr[e + u];                  // scalar load (uniform addr, padded array)
                    id[u] = (e + u < e1) ? raw : N_NODES_C;
                }
                #pragma unroll
                for (int u = 0; u < 16; u++) {
                    float2 g2 = __half22float2(*(const __half2*)&yh[(long)id[u] * HID + j]);
                    acc0 += g2.x; acc1 += g2.y;
                }
                e += 16;
            } while (e < e1);
            const float ni = norm[i];
            float2 bi = *(const float2*)&bias[j];
            float2 me = *(const float2*)&mean[j];
            float2 ga = *(const float2*)&gam[j];
            float2 va = *(const float2*)&varr[j];
            float2 be = *(const float2*)&bet[j];
            float v0 = (acc0 * ni + bi.x - me.x) * (ga.x * rsqrtf(va.x + BN_EPS_C)) + be.x;
            float v1 = (acc1 * ni + bi.y - me.y) * (ga.y * rsqrtf(va.y + BN_EPS_C)) + be.y;
            *(__half2*)&h[(long)i * HID + j] = __floats2half2_rn(fmaxf(v0, 0.f), fmaxf(v1, 0.f));
        }
        grid.sync();
    }

    // ---------- pool: 2 units of 32 nodes per block ----------
    const int sub = tid >> 7, t7 = tid & 127;
    for (int u = 2 * bid + sub; u < PU_C; u += 2 * G) {
        const int i0 = u * 32;
        const int iend = min(i0 + 32, N_NODES_C);
        float acc = 0.f;
        int cur = batch[i0];
        int runStart = i0;
        for (int i = i0; i < iend; i++) {
            int g = batch[i];
            if (g != cur) {
                atomicAdd(&psum[(long)cur * HID + t7], acc);
                if (t7 == 0) atomicAdd(&pcount[cur], i - runStart);
                acc = 0.f; cur = g; runStart = i;
            }
            acc += __half2float(h[(long)i * HID + t7]);
        }
        atomicAdd(&psum[(long)cur * HID + t7], acc);
        if (t7 == 0) atomicAdd(&pcount[cur], iend - runStart);
    }
    grid.sync();

    // ---------- final: 2 graphs per block ----------
    for (int base = 2 * bid; base < N_GRAPHS_C; base += 2 * G) {
        const int g = base + sub;          // N_GRAPHS even -> g always valid
        float cnt = fmaxf((float)pcount[g], 1.f);
        float p = psum[(long)g * HID + t7] / cnt;
        #pragma unroll
        for (int o = 0; o < 5; o++) sm.red[sub][t7][o] = p * W_out[t7 * 5 + o];
        __syncthreads();
        for (int off = 64; off >= 1; off >>= 1) {
            if (t7 < off) {
                #pragma unroll
                for (int o = 0; o < 5; o++) sm.red[sub][t7][o] += sm.red[sub][t7 + off][o];
            }
            __syncthreads();
        }
        if (t7 < 5) out[g * 5 + t7] = sm.red[sub][0][t7] + b_out[t7];
        __syncthreads();
    }
}

// ---------------- launch ----------------

extern "C" void kernel_launch(void* const* d_in, const int* in_sizes, int n_in,
                              void* d_out, int out_size, void* d_ws, size_t ws_size,
                              hipStream_t stream) {
    const float* x        = (const float*)d_in[0];
    const int*   eidx     = (const int*)d_in[1];
    const int*   batch    = (const int*)d_in[2];
    const float* Ws_all   = (const float*)d_in[3];
    const float* bs       = (const float*)d_in[4];
    const float* gammas   = (const float*)d_in[5];
    const float* betas    = (const float*)d_in[6];
    const float* run_mean = (const float*)d_in[7];
    const float* run_var  = (const float*)d_in[8];
    const float* W_out    = (const float*)d_in[9];
    const float* b_out    = (const float*)d_in[10];
    float* out = (float*)d_out;
    char* ws = (char*)d_ws;

    int nb = 0;
    if (hipOccupancyMaxActiveBlocksPerMultiprocessor(&nb, k_mega, 256, 0) != hipSuccess || nb < 1) nb = 2;
    if (nb > 8) nb = 8;
    unsigned grid = (unsigned)nb * 256u;   // 256 CUs on MI355X

    void* args[] = {(void*)&x, (void*)&eidx, (void*)&batch, (void*)&Ws_all, (void*)&bs,
                    (void*)&gammas, (void*)&betas, (void*)&run_mean, (void*)&run_var,
                    (void*)&W_out, (void*)&b_out, (void*)&out, (void*)&ws};
    hipLaunchCooperativeKernel(k_mega, dim3(grid), dim3(256), args, 0, stream);
}

// Round 9
// 458.829 us; speedup vs baseline: 3.5027x; 3.5027x over previous
//
#include <hip/hip_runtime.h>
#include <hip/hip_fp16.h>

#define N_NODES_C 100000
#define N_EDGES_C 1600000
#define N_GRAPHS_C 2000
#define HID 128
#define BN_EPS_C 1e-5f
#define NBUCK 391          // ceil(100000 / 256) buckets of 256 nodes
#define PART_TILE 4096     // edges per block in hist/partition kernels

typedef _Float16 half8 __attribute__((ext_vector_type(8)));
typedef float float4v __attribute__((ext_vector_type(4)));

// ---------------- CSR build: bucket partition (packed 4B ebuf) ----------------
// k_twhist: W-transpose slice + yB-dummy-row zero + dst-bucket histogram in one kernel.

__global__ __launch_bounds__(256) void k_twhist(const float* __restrict__ Ws_all, _Float16* __restrict__ WT,
                                                const int* __restrict__ dst, int* __restrict__ bcount,
                                                _Float16* __restrict__ yB_dummy) {
    const int t = threadIdx.x;
    // --- W transpose: 65536 elements over 391*256 threads (single shot) ---
    int idx = blockIdx.x * 256 + t;
    if (idx < 4 * HID * HID) {
        int l = idx >> 14, r = idx & 16383, k = r >> 7, n = r & 127;
        WT[l * 16384 + n * HID + k] = (_Float16)Ws_all[idx];
    }
    if (blockIdx.x == 390 && t < 64) ((int*)yB_dummy)[t] = 0;   // zero yB dummy row (256B)
    // --- histogram ---
    __shared__ int hist[NBUCK];
    for (int b = t; b < NBUCK; b += 256) hist[b] = 0;
    __syncthreads();
    const int e0 = blockIdx.x * PART_TILE;
    #pragma unroll
    for (int k = 0; k < 16; k++) {
        int e = e0 + k * 256 + t;
        if (e < N_EDGES_C) atomicAdd(&hist[dst[e] >> 8], 1);
    }
    __syncthreads();
    for (int b = t; b < NBUCK; b += 256) {
        int c = hist[b];
        if (c) atomicAdd(&bcount[b], c);
    }
}

__global__ __launch_bounds__(512) void kb_scan(const int* __restrict__ bcount,
                                               int* __restrict__ bbase, int* __restrict__ bcursor) {
    __shared__ int s[512];
    const int t = threadIdx.x;
    int v = (t < NBUCK) ? bcount[t] : 0;
    s[t] = v;
    __syncthreads();
    for (int off = 1; off < 512; off <<= 1) {
        int u = (t >= off) ? s[t - off] : 0;
        __syncthreads();
        s[t] += u;
        __syncthreads();
    }
    if (t < NBUCK) { int e = s[t] - v; bbase[t] = e; bcursor[t] = e; }
    if (t == 0) bbase[NBUCK] = N_EDGES_C;
}

// ebuf entry: (src << 8) | (dst & 255)
__global__ __launch_bounds__(256) void kb_part(const int* __restrict__ src, const int* __restrict__ dst,
                                               int* __restrict__ bcursor, int* __restrict__ ebuf) {
    __shared__ int hist[NBUCK];
    __shared__ int startA[NBUCK];
    __shared__ int lcur[NBUCK];
    const int t = threadIdx.x;
    for (int b = t; b < NBUCK; b += 256) { hist[b] = 0; lcur[b] = 0; }
    __syncthreads();
    const int e0 = blockIdx.x * PART_TILE;
    #pragma unroll
    for (int k = 0; k < 16; k++) {
        int e = e0 + k * 256 + t;
        if (e < N_EDGES_C) atomicAdd(&hist[dst[e] >> 8], 1);
    }
    __syncthreads();
    for (int b = t; b < NBUCK; b += 256) {
        int c = hist[b];
        startA[b] = c ? atomicAdd(&bcursor[b], c) : 0;
    }
    __syncthreads();
    #pragma unroll
    for (int k = 0; k < 16; k++) {
        int e = e0 + k * 256 + t;
        if (e < N_EDGES_C) {
            int d = dst[e];
            int b = d >> 8;
            int pos = startA[b] + atomicAdd(&lcur[b], 1);
            ebuf[pos] = (src[e] << 8) | (d & 255);
        }
    }
}

__global__ __launch_bounds__(256) void kb_fill(const int* __restrict__ ebuf, const int* __restrict__ bbase,
                                               int* __restrict__ csr_src, int* __restrict__ offs,
                                               float* __restrict__ norm) {
    __shared__ int s[256];
    __shared__ int excl[256];
    __shared__ int lcur[256];
    const int b = blockIdx.x, t = threadIdx.x;
    const int base = b << 8;
    const int e0 = bbase[b], e1 = bbase[b + 1];
    s[t] = 0; lcur[t] = 0;
    __syncthreads();
    for (int e = e0 + t; e < e1; e += 256)
        atomicAdd(&s[ebuf[e] & 255], 1);
    __syncthreads();
    int own = s[t];
    for (int off = 1; off < 256; off <<= 1) {
        int v = (t >= off) ? s[t - off] : 0;
        __syncthreads();
        s[t] += v;
        __syncthreads();
    }
    excl[t] = s[t] - own;
    int node = base + t;
    if (node < N_NODES_C) {
        offs[node] = e0 + (s[t] - own);
        norm[node] = rsqrtf((float)own + 1.0f);
    }
    if (b == 0 && t == 0) offs[N_NODES_C] = N_EDGES_C;
    __syncthreads();
    for (int e = e0 + t; e < e1; e += 256) {
        int p = ebuf[e];
        int l = p & 255;
        int pos = e0 + excl[l] + atomicAdd(&lcur[l], 1);
        csr_src[pos] = p >> 8;
    }
}

// ---------------- layer-0 GEMM (f32 input x): Y = norm .* (x @ W0), fp16 out ----------------
// Rows >= nrows store zeros -> provides the zeroed dummy row at index N_NODES in yA.

__global__ __launch_bounds__(256) void k_gemm0(const float* __restrict__ Ap,
                                               const _Float16* __restrict__ WT,
                                               const float* __restrict__ norm,
                                               _Float16* __restrict__ Y, int nrows) {
    __shared__ _Float16 Wt[HID][136];
    const int tid = threadIdx.x;
    #pragma unroll
    for (int t = 0; t < 8; t++) {
        int off = tid * 8 + t * 2048;
        *(half8*)&Wt[off >> 7][off & 127] = *(const half8*)&WT[off];
    }
    __syncthreads();

    const int wave = tid >> 6, lane = tid & 63, quad = lane >> 4, l16 = lane & 15;
    half8 Wf[2][4];
    #pragma unroll
    for (int c = 0; c < 2; c++)
        #pragma unroll
        for (int ks = 0; ks < 4; ks++)
            Wf[c][ks] = *(const half8*)&Wt[(wave * 2 + c) * 16 + l16][ks * 32 + quad * 8];

    const int nbase = blockIdx.x * 128;
    #pragma unroll
    for (int t = 0; t < 8; t++) {
        int node = nbase + t * 16 + l16;
        bool ok = node < nrows;
        half8 Af[4];
        const float* arow = Ap + (long)node * HID;
        #pragma unroll
        for (int ks = 0; ks < 4; ks++) {
            if (ok) {
                float4 fa = *(const float4*)&arow[ks * 32 + quad * 8];
                float4 fb = *(const float4*)&arow[ks * 32 + quad * 8 + 4];
                _Float16 pk[8] = {(_Float16)fa.x, (_Float16)fa.y, (_Float16)fa.z, (_Float16)fa.w,
                                  (_Float16)fb.x, (_Float16)fb.y, (_Float16)fb.z, (_Float16)fb.w};
                Af[ks] = *(half8*)pk;
            } else Af[ks] = half8{};
        }
        float4v a0 = {0.f, 0.f, 0.f, 0.f}, a1 = {0.f, 0.f, 0.f, 0.f};
        #pragma unroll
        for (int ks = 0; ks < 4; ks++) {
            a0 = __builtin_amdgcn_mfma_f32_16x16x32_f16(Wf[0][ks], Af[ks], a0, 0, 0, 0);
            a1 = __builtin_amdgcn_mfma_f32_16x16x32_f16(Wf[1][ks], Af[ks], a1, 0, 0, 0);
        }
        float nv = ok ? norm[node] : 0.f;
        _Float16 p0[4], p1[4];
        #pragma unroll
        for (int r = 0; r < 4; r++) {
            p0[r] = (_Float16)(a0[r] * nv);
            p1[r] = (_Float16)(a1[r] * nv);
        }
        *(ushort4*)&Y[(long)node * HID + (wave * 2 + 0) * 16 + quad * 4] = *(ushort4*)p0;
        *(ushort4*)&Y[(long)node * HID + (wave * 2 + 1) * 16 + quad * 4] = *(ushort4*)p1;
    }
}

// ---------------- Fused agg(l) [+ gemm(l+1) | + pool] ----------------
// 512 threads / 8 waves per block, 32 nodes per block (3125 blocks).
// Agg phase = proven r3 body, wave per node (4 serial nodes/wave); h -> LDS only.
// !LAST: block-local 32x128 MFMA gemm with W frags straight from L2-hot WT; y' = norm.*(h@W).
// LAST:  run-length pool of the block's 32 sorted nodes into psum/pcount.

template<bool LAST>
__global__ __launch_bounds__(512, 8) void k_fused(
    const __half* __restrict__ yin, _Float16* __restrict__ yout,
    const _Float16* __restrict__ WTn, const int* __restrict__ offs,
    const int* __restrict__ csr, const float* __restrict__ norm,
    const float* __restrict__ bias, const float* __restrict__ mean,
    const float* __restrict__ gam, const float* __restrict__ varr,
    const float* __restrict__ bet, const int* __restrict__ batch,
    float* __restrict__ psum, int* __restrict__ pcount)
{
    __shared__ __half ht[32][136];   // pitch 136 halves (272B = 16*17 -> 16B-aligned rows, bank-spread)
    const int tid = threadIdx.x;
    const int wv = __builtin_amdgcn_readfirstlane(tid >> 6);
    const int lane = tid & 63;
    const int j = lane * 2;
    const int nbase = blockIdx.x * 32;

    // ---- agg: wave wv handles nodes nbase+wv*4 .. +4 (serially) ----
    for (int r = 0; r < 4; r++) {
        const int li = wv * 4 + r;
        const int i = nbase + li;
        float2 f = __half22float2(*(const __half2*)&yin[(long)i * HID + j]);
        float acc0 = f.x, acc1 = f.y;
        const int e0 = offs[i], e1 = offs[i + 1];
        int e = e0;
        do {
            int id[16];
            #pragma unroll
            for (int u = 0; u < 16; u++) {
                int raw = csr[e + u];                    // scalar load (wave-uniform addr)
                id[u] = (e + u < e1) ? raw : N_NODES_C;  // cselect -> zeroed dummy row
            }
            #pragma unroll
            for (int u = 0; u < 16; u++) {
                float2 g2 = __half22float2(*(const __half2*)&yin[(long)id[u] * HID + j]);
                acc0 += g2.x; acc1 += g2.y;
            }
            e += 16;
        } while (e < e1);
        const float ni = norm[i];
        float2 bi = *(const float2*)&bias[j];
        float2 me = *(const float2*)&mean[j];
        float2 ga = *(const float2*)&gam[j];
        float2 va = *(const float2*)&varr[j];
        float2 be = *(const float2*)&bet[j];
        float v0 = (acc0 * ni + bi.x - me.x) * (ga.x * rsqrtf(va.x + BN_EPS_C)) + be.x;
        float v1 = (acc1 * ni + bi.y - me.y) * (ga.y * rsqrtf(va.y + BN_EPS_C)) + be.y;
        *(__half2*)&ht[li][j] = __floats2half2_rn(fmaxf(v0, 0.f), fmaxf(v1, 0.f));
    }
    __syncthreads();

    if constexpr (!LAST) {
        // ---- gemm: wave wv owns channel group [wv*16, wv*16+16) for both 16-node groups ----
        const int quad = lane >> 4, l16 = lane & 15;
        half8 Wf[4];
        #pragma unroll
        for (int ks = 0; ks < 4; ks++)
            Wf[ks] = *(const half8*)&WTn[(long)(wv * 16 + l16) * HID + ks * 32 + quad * 8];
        #pragma unroll
        for (int ng = 0; ng < 2; ng++) {
            half8 Af[4];
            #pragma unroll
            for (int ks = 0; ks < 4; ks++)
                Af[ks] = *(const half8*)&ht[ng * 16 + l16][ks * 32 + quad * 8];
            float4v a0 = {0.f, 0.f, 0.f, 0.f};
            #pragma unroll
            for (int ks = 0; ks < 4; ks++)
                a0 = __builtin_amdgcn_mfma_f32_16x16x32_f16(Wf[ks], Af[ks], a0, 0, 0, 0);
            const int node = nbase + ng * 16 + l16;
            const float nv = norm[node];
            _Float16 p[4];
            #pragma unroll
            for (int r = 0; r < 4; r++) p[r] = (_Float16)(a0[r] * nv);
            *(ushort4*)&yout[(long)node * HID + wv * 16 + quad * 4] = *(ushort4*)p;
        }
    } else {
        // ---- pool: 4 sub-groups of 128 threads, each run-lengths 8 sorted nodes ----
        const int sub = tid >> 7, t7 = tid & 127;
        const int i0 = nbase + sub * 8, iend = i0 + 8;
        float acc = 0.f;
        int cur = batch[i0];
        int runStart = i0;
        for (int i = i0; i < iend; i++) {
            int g = batch[i];
            if (g != cur) {
                atomicAdd(&psum[(long)cur * HID + t7], acc);
                if (t7 == 0) atomicAdd(&pcount[cur], i - runStart);
                acc = 0.f; cur = g; runStart = i;
            }
            acc += __half2float(ht[i - nbase][t7]);
        }
        atomicAdd(&psum[(long)cur * HID + t7], acc);
        if (t7 == 0) atomicAdd(&pcount[cur], iend - runStart);
    }
}

__global__ __launch_bounds__(128) void k_final(const float* __restrict__ psum, const int* __restrict__ pcount,
                                               const float* __restrict__ W_out, const float* __restrict__ b_out,
                                               float* __restrict__ out) {
    __shared__ float red[128][5];
    const int g = blockIdx.x, j = threadIdx.x;
    float cnt = fmaxf((float)pcount[g], 1.f);
    float p = psum[(long)g * HID + j] / cnt;
    #pragma unroll
    for (int o = 0; o < 5; o++) red[j][o] = p * W_out[j * 5 + o];
    __syncthreads();
    for (int off = 64; off >= 1; off >>= 1) {
        if (j < off) {
            #pragma unroll
            for (int o = 0; o < 5; o++) red[j][o] += red[j + off][o];
        }
        __syncthreads();
    }
    if (j < 5) out[g * 5 + j] = red[0][j] + b_out[j];
}

// ---------------- launch ----------------

extern "C" void kernel_launch(void* const* d_in, const int* in_sizes, int n_in,
                              void* d_out, int out_size, void* d_ws, size_t ws_size,
                              hipStream_t stream) {
    const float* x        = (const float*)d_in[0];
    const int*   eidx     = (const int*)d_in[1];
    const int*   src      = eidx;
    const int*   dst      = eidx + N_EDGES_C;
    const int*   batch    = (const int*)d_in[2];
    const float* Ws_all   = (const float*)d_in[3];
    const float* bs       = (const float*)d_in[4];
    const float* gammas   = (const float*)d_in[5];
    const float* betas    = (const float*)d_in[6];
    const float* run_mean = (const float*)d_in[7];
    const float* run_var  = (const float*)d_in[8];
    const float* W_out    = (const float*)d_in[9];
    const float* b_out    = (const float*)d_in[10];
    float* out = (float*)d_out;

    char* wp = (char*)d_ws;
    auto alloc = [&](size_t bytes) { char* p = wp; wp += (bytes + 255) & ~(size_t)255; return p; };
    _Float16* yA      = (_Float16*)alloc((size_t)(N_NODES_C + 128) * HID * 2);  // dummy row zeroed by k_gemm0
    _Float16* yB      = (_Float16*)alloc((size_t)(N_NODES_C + 128) * HID * 2);  // dummy row zeroed by k_twhist
    int*      ebuf    = (int*)yA;                 // alias: packed edges, dead before k_gemm0 writes yA
    _Float16* WT      = (_Float16*)alloc((size_t)4 * HID * HID * 2);
    int*      csr_src = (int*)alloc((size_t)(N_EDGES_C + 16) * 4);  // +16 pad for 16-wide chain overread
    int*      offs    = (int*)alloc((size_t)(N_NODES_C + 1) * 4);
    float*    norm    = (float*)alloc((size_t)N_NODES_C * 4);
    int*      bbase   = (int*)alloc((NBUCK + 1) * 4);
    int*      bcursor = (int*)alloc((NBUCK + 1) * 4);
    // zero-init group: psum | pcount | bcount contiguous -> ONE memset
    char*     zbeg    = wp;
    float*    psum    = (float*)alloc((size_t)N_GRAPHS_C * HID * 4);
    int*      pcount  = (int*)alloc((size_t)N_GRAPHS_C * 4);
    int*      bcount  = (int*)alloc((NBUCK + 1) * 4);
    size_t    zlen    = (size_t)(wp - zbeg);

    hipMemsetAsync(zbeg, 0, zlen, stream);

    const int PB = (N_EDGES_C + PART_TILE - 1) / PART_TILE;  // 391
    k_twhist<<<PB, 256, 0, stream>>>(Ws_all, WT, dst, bcount, yB + (size_t)N_NODES_C * HID);
    kb_scan <<<1, 512, 0, stream>>>(bcount, bbase, bcursor);
    kb_part <<<PB, 256, 0, stream>>>(src, dst, bcursor, ebuf);
    kb_fill <<<NBUCK, 256, 0, stream>>>(ebuf, bbase, csr_src, offs, norm);

    const int GB = (N_NODES_C + 127) / 128;   // 782
    const int FB = N_NODES_C / 32;            // 3125
    k_gemm0<<<GB, 256, 0, stream>>>(x, WT, norm, yA, N_NODES_C);

    // F1: agg(0) + gemm(1): yA -> yB
    k_fused<false><<<FB, 512, 0, stream>>>((const __half*)yA, yB, WT + 1 * 16384, offs, csr_src, norm,
                                           bs + 0 * HID, run_mean + 0 * HID, gammas + 0 * HID,
                                           run_var + 0 * HID, betas + 0 * HID, nullptr, nullptr, nullptr);
    // F2: agg(1) + gemm(2): yB -> yA
    k_fused<false><<<FB, 512, 0, stream>>>((const __half*)yB, yA, WT + 2 * 16384, offs, csr_src, norm,
                                           bs + 1 * HID, run_mean + 1 * HID, gammas + 1 * HID,
                                           run_var + 1 * HID, betas + 1 * HID, nullptr, nullptr, nullptr);
    // F3: agg(2) + gemm(3): yA -> yB
    k_fused<false><<<FB, 512, 0, stream>>>((const __half*)yA, yB, WT + 3 * 16384, offs, csr_src, norm,
                                           bs + 2 * HID, run_mean + 2 * HID, gammas + 2 * HID,
                                           run_var + 2 * HID, betas + 2 * HID, nullptr, nullptr, nullptr);
    // F4: agg(3) + pool: yB -> psum/pcount
    k_fused<true><<<FB, 512, 0, stream>>>((const __half*)yB, nullptr, nullptr, offs, csr_src, norm,
                                          bs + 3 * HID, run_mean + 3 * HID, gammas + 3 * HID,
                                          run_var + 3 * HID, betas + 3 * HID, batch, psum, pcount);

    k_final<<<N_GRAPHS_C, 128, 0, stream>>>(psum, pcount, W_out, b_out, out);
}

// Round 10
// 447.227 us; speedup vs baseline: 3.5935x; 1.0259x over previous
//
#include <hip/hip_runtime.h>
#include <hip/hip_fp16.h>

#define N_NODES_C 100000
#define N_EDGES_C 1600000
#define N_GRAPHS_C 2000
#define HID 128
#define BN_EPS_C 1e-5f
#define NBUCK 391          // ceil(100000 / 256) buckets of 256 nodes
#define PART_TILE 4096     // edges per block in hist/partition kernels

typedef _Float16 half8 __attribute__((ext_vector_type(8)));
typedef float float4v __attribute__((ext_vector_type(4)));

// ---------------- CSR build: bucket partition (packed 4B ebuf) ----------------
// k_twhist: W-transpose slice + yB-dummy-row zero + dst-bucket histogram in one kernel.

__global__ __launch_bounds__(256) void k_twhist(const float* __restrict__ Ws_all, _Float16* __restrict__ WT,
                                                const int* __restrict__ dst, int* __restrict__ bcount,
                                                _Float16* __restrict__ yB_dummy) {
    const int t = threadIdx.x;
    // --- W transpose: 65536 elements over 391*256 threads (single shot) ---
    int idx = blockIdx.x * 256 + t;
    if (idx < 4 * HID * HID) {
        int l = idx >> 14, r = idx & 16383, k = r >> 7, n = r & 127;
        WT[l * 16384 + n * HID + k] = (_Float16)Ws_all[idx];
    }
    if (blockIdx.x == 390 && t < 64) ((int*)yB_dummy)[t] = 0;   // zero yB dummy row (256B)
    // --- histogram ---
    __shared__ int hist[NBUCK];
    for (int b = t; b < NBUCK; b += 256) hist[b] = 0;
    __syncthreads();
    const int e0 = blockIdx.x * PART_TILE;
    #pragma unroll
    for (int k = 0; k < 16; k++) {
        int e = e0 + k * 256 + t;
        if (e < N_EDGES_C) atomicAdd(&hist[dst[e] >> 8], 1);
    }
    __syncthreads();
    for (int b = t; b < NBUCK; b += 256) {
        int c = hist[b];
        if (c) atomicAdd(&bcount[b], c);
    }
}

// ebuf entry: (src << 8) | (dst & 255). Scan of bcount recomputed per block in LDS
// (replaces the kb_scan dispatch); space claimed via bbase_local + relative cursor.
__global__ __launch_bounds__(256) void kb_part(const int* __restrict__ src, const int* __restrict__ dst,
                                               const int* __restrict__ bcount, int* __restrict__ relcur,
                                               int* __restrict__ ebuf) {
    __shared__ int sb[512];          // exclusive scan of bcount
    __shared__ int hist[NBUCK];
    __shared__ int startA[NBUCK];
    __shared__ int lcur[NBUCK];
    const int t = threadIdx.x;
    int v0 = (t < NBUCK) ? bcount[t] : 0;
    int v1 = (t + 256 < NBUCK) ? bcount[t + 256] : 0;
    sb[t] = v0; sb[t + 256] = v1;
    for (int b = t; b < NBUCK; b += 256) { hist[b] = 0; lcur[b] = 0; }
    __syncthreads();
    for (int off = 1; off < 512; off <<= 1) {
        int a  = (t >= off) ? sb[t - off] : 0;
        int b2 = (t + 256 >= off) ? sb[t + 256 - off] : 0;
        __syncthreads();
        sb[t] += a; sb[t + 256] += b2;
        __syncthreads();
    }
    sb[t] -= v0; sb[t + 256] -= v1;   // inclusive -> exclusive
    __syncthreads();
    const int e0 = blockIdx.x * PART_TILE;
    #pragma unroll
    for (int k = 0; k < 16; k++) {
        int e = e0 + k * 256 + t;
        if (e < N_EDGES_C) atomicAdd(&hist[dst[e] >> 8], 1);
    }
    __syncthreads();
    for (int b = t; b < NBUCK; b += 256) {
        int c = hist[b];
        startA[b] = c ? (sb[b] + atomicAdd(&relcur[b], c)) : 0;
    }
    __syncthreads();
    #pragma unroll
    for (int k = 0; k < 16; k++) {
        int e = e0 + k * 256 + t;
        if (e < N_EDGES_C) {
            int d = dst[e];
            int b = d >> 8;
            int pos = startA[b] + atomicAdd(&lcur[b], 1);
            ebuf[pos] = (src[e] << 8) | (d & 255);
        }
    }
}

__global__ __launch_bounds__(256) void kb_fill(const int* __restrict__ ebuf, const int* __restrict__ bcount,
                                               int* __restrict__ csr_src, int* __restrict__ offs,
                                               float* __restrict__ norm) {
    __shared__ int sb[512];          // exclusive scan of bcount
    __shared__ int s[256];
    __shared__ int excl[256];
    __shared__ int lcur[256];
    const int b = blockIdx.x, t = threadIdx.x;
    int v0 = (t < NBUCK) ? bcount[t] : 0;
    int v1 = (t + 256 < NBUCK) ? bcount[t + 256] : 0;
    sb[t] = v0; sb[t + 256] = v1;
    s[t] = 0; lcur[t] = 0;
    __syncthreads();
    for (int off = 1; off < 512; off <<= 1) {
        int a  = (t >= off) ? sb[t - off] : 0;
        int b2 = (t + 256 >= off) ? sb[t + 256 - off] : 0;
        __syncthreads();
        sb[t] += a; sb[t + 256] += b2;
        __syncthreads();
    }
    sb[t] -= v0; sb[t + 256] -= v1;
    __syncthreads();
    const int base = b << 8;
    const int e0 = sb[b], e1 = sb[b] + bcount[b];
    for (int e = e0 + t; e < e1; e += 256)
        atomicAdd(&s[ebuf[e] & 255], 1);
    __syncthreads();
    int own = s[t];
    for (int off = 1; off < 256; off <<= 1) {
        int v = (t >= off) ? s[t - off] : 0;
        __syncthreads();
        s[t] += v;
        __syncthreads();
    }
    excl[t] = s[t] - own;
    int node = base + t;
    if (node < N_NODES_C) {
        offs[node] = e0 + (s[t] - own);
        norm[node] = rsqrtf((float)own + 1.0f);
    }
    if (b == 0 && t == 0) offs[N_NODES_C] = N_EDGES_C;
    __syncthreads();
    for (int e = e0 + t; e < e1; e += 256) {
        int p = ebuf[e];
        int l = p & 255;
        int pos = e0 + excl[l] + atomicAdd(&lcur[l], 1);
        csr_src[pos] = p >> 8;
    }
}

// ---------------- layer-0 GEMM (f32 input x): Y = norm .* (x @ W0), fp16 out ----------------
// Rows >= nrows store zeros -> provides the zeroed dummy row at index N_NODES in yA.

__global__ __launch_bounds__(256) void k_gemm0(const float* __restrict__ Ap,
                                               const _Float16* __restrict__ WT,
                                               const float* __restrict__ norm,
                                               _Float16* __restrict__ Y, int nrows) {
    __shared__ _Float16 Wt[HID][136];
    const int tid = threadIdx.x;
    #pragma unroll
    for (int t = 0; t < 8; t++) {
        int off = tid * 8 + t * 2048;
        *(half8*)&Wt[off >> 7][off & 127] = *(const half8*)&WT[off];
    }
    __syncthreads();

    const int wave = tid >> 6, lane = tid & 63, quad = lane >> 4, l16 = lane & 15;
    half8 Wf[2][4];
    #pragma unroll
    for (int c = 0; c < 2; c++)
        #pragma unroll
        for (int ks = 0; ks < 4; ks++)
            Wf[c][ks] = *(const half8*)&Wt[(wave * 2 + c) * 16 + l16][ks * 32 + quad * 8];

    const int nbase = blockIdx.x * 128;
    #pragma unroll
    for (int t = 0; t < 8; t++) {
        int node = nbase + t * 16 + l16;
        bool ok = node < nrows;
        half8 Af[4];
        const float* arow = Ap + (long)node * HID;
        #pragma unroll
        for (int ks = 0; ks < 4; ks++) {
            if (ok) {
                float4 fa = *(const float4*)&arow[ks * 32 + quad * 8];
                float4 fb = *(const float4*)&arow[ks * 32 + quad * 8 + 4];
                _Float16 pk[8] = {(_Float16)fa.x, (_Float16)fa.y, (_Float16)fa.z, (_Float16)fa.w,
                                  (_Float16)fb.x, (_Float16)fb.y, (_Float16)fb.z, (_Float16)fb.w};
                Af[ks] = *(half8*)pk;
            } else Af[ks] = half8{};
        }
        float4v a0 = {0.f, 0.f, 0.f, 0.f}, a1 = {0.f, 0.f, 0.f, 0.f};
        #pragma unroll
        for (int ks = 0; ks < 4; ks++) {
            a0 = __builtin_amdgcn_mfma_f32_16x16x32_f16(Wf[0][ks], Af[ks], a0, 0, 0, 0);
            a1 = __builtin_amdgcn_mfma_f32_16x16x32_f16(Wf[1][ks], Af[ks], a1, 0, 0, 0);
        }
        float nv = ok ? norm[node] : 0.f;
        _Float16 p0[4], p1[4];
        #pragma unroll
        for (int r = 0; r < 4; r++) {
            p0[r] = (_Float16)(a0[r] * nv);
            p1[r] = (_Float16)(a1[r] * nv);
        }
        *(ushort4*)&Y[(long)node * HID + (wave * 2 + 0) * 16 + quad * 4] = *(ushort4*)p0;
        *(ushort4*)&Y[(long)node * HID + (wave * 2 + 1) * 16 + quad * 4] = *(ushort4*)p1;
    }
}

// ---------------- Fused agg(l) [+ gemm(l+1) | + pool] ----------------
// 512 threads / 8 waves per block, 32 nodes per block (3125 blocks).
// W fragments PREFETCHED at kernel entry (hides WT global latency under the agg phase).
// Agg = proven r3 body; h -> LDS only. !LAST: block-local 32x128 MFMA gemm.
// LAST: run-length pool of the block's 32 sorted nodes into psum/pcount.

template<bool LAST>
__global__ __launch_bounds__(512, 8) void k_fused(
    const __half* __restrict__ yin, _Float16* __restrict__ yout,
    const _Float16* __restrict__ WTn, const int* __restrict__ offs,
    const int* __restrict__ csr, const float* __restrict__ norm,
    const float* __restrict__ bias, const float* __restrict__ mean,
    const float* __restrict__ gam, const float* __restrict__ varr,
    const float* __restrict__ bet, const int* __restrict__ batch,
    float* __restrict__ psum, int* __restrict__ pcount)
{
    __shared__ __half ht[32][136];   // pitch 136 halves (272B rows: 2-way bank alias = free)
    const int tid = threadIdx.x;
    const int wv = __builtin_amdgcn_readfirstlane(tid >> 6);
    const int lane = tid & 63;
    const int quad = lane >> 4, l16 = lane & 15;
    const int j = lane * 2;
    const int nbase = blockIdx.x * 32;

    half8 Wf[4];
    if constexpr (!LAST) {
        #pragma unroll
        for (int ks = 0; ks < 4; ks++)   // prefetch: in flight during the whole agg phase
            Wf[ks] = *(const half8*)&WTn[(long)(wv * 16 + l16) * HID + ks * 32 + quad * 8];
    }

    // ---- agg: wave wv handles nodes nbase+wv*4 .. +4 (serially) ----
    for (int r = 0; r < 4; r++) {
        const int li = wv * 4 + r;
        const int i = nbase + li;
        float2 f = __half22float2(*(const __half2*)&yin[(long)i * HID + j]);
        float acc0 = f.x, acc1 = f.y;
        const int e0 = offs[i], e1 = offs[i + 1];
        int e = e0;
        do {
            int id[16];
            #pragma unroll
            for (int u = 0; u < 16; u++) {
                int raw = csr[e + u];                    // scalar load (wave-uniform addr)
                id[u] = (e + u < e1) ? raw : N_NODES_C;  // cselect -> zeroed dummy row
            }
            #pragma unroll
            for (int u = 0; u < 16; u++) {
                float2 g2 = __half22float2(*(const __half2*)&yin[(long)id[u] * HID + j]);
                acc0 += g2.x; acc1 += g2.y;
            }
            e += 16;
        } while (e < e1);
        const float ni = norm[i];
        float2 bi = *(const float2*)&bias[j];
        float2 me = *(const float2*)&mean[j];
        float2 ga = *(const float2*)&gam[j];
        float2 va = *(const float2*)&varr[j];
        float2 be = *(const float2*)&bet[j];
        float v0 = (acc0 * ni + bi.x - me.x) * (ga.x * rsqrtf(va.x + BN_EPS_C)) + be.x;
        float v1 = (acc1 * ni + bi.y - me.y) * (ga.y * rsqrtf(va.y + BN_EPS_C)) + be.y;
        *(__half2*)&ht[li][j] = __floats2half2_rn(fmaxf(v0, 0.f), fmaxf(v1, 0.f));
    }
    __syncthreads();

    if constexpr (!LAST) {
        // ---- gemm: wave wv owns channel group [wv*16, wv*16+16) for both 16-node groups ----
        #pragma unroll
        for (int ng = 0; ng < 2; ng++) {
            half8 Af[4];
            #pragma unroll
            for (int ks = 0; ks < 4; ks++)
                Af[ks] = *(const half8*)&ht[ng * 16 + l16][ks * 32 + quad * 8];
            float4v a0 = {0.f, 0.f, 0.f, 0.f};
            #pragma unroll
            for (int ks = 0; ks < 4; ks++)
                a0 = __builtin_amdgcn_mfma_f32_16x16x32_f16(Wf[ks], Af[ks], a0, 0, 0, 0);
            const int node = nbase + ng * 16 + l16;
            const float nv = norm[node];
            _Float16 p[4];
            #pragma unroll
            for (int r = 0; r < 4; r++) p[r] = (_Float16)(a0[r] * nv);
            *(ushort4*)&yout[(long)node * HID + wv * 16 + quad * 4] = *(ushort4*)p;
        }
    } else {
        // ---- pool: 4 sub-groups of 128 threads, each run-lengths 8 sorted nodes ----
        const int sub = tid >> 7, t7 = tid & 127;
        const int i0 = nbase + sub * 8, iend = i0 + 8;
        float acc = 0.f;
        int cur = batch[i0];
        int runStart = i0;
        for (int i = i0; i < iend; i++) {
            int g = batch[i];
            if (g != cur) {
                atomicAdd(&psum[(long)cur * HID + t7], acc);
                if (t7 == 0) atomicAdd(&pcount[cur], i - runStart);
                acc = 0.f; cur = g; runStart = i;
            }
            acc += __half2float(ht[i - nbase][t7]);
        }
        atomicAdd(&psum[(long)cur * HID + t7], acc);
        if (t7 == 0) atomicAdd(&pcount[cur], iend - runStart);
    }
}

__global__ __launch_bounds__(128) void k_final(const float* __restrict__ psum, const int* __restrict__ pcount,
                                               const float* __restrict__ W_out, const float* __restrict__ b_out,
                                               float* __restrict__ out) {
    __shared__ float red[128][5];
    const int g = blockIdx.x, j = threadIdx.x;
    float cnt = fmaxf((float)pcount[g], 1.f);
    float p = psum[(long)g * HID + j] / cnt;
    #pragma unroll
    for (int o = 0; o < 5; o++) red[j][o] = p * W_out[j * 5 + o];
    __syncthreads();
    for (int off = 64; off >= 1; off >>= 1) {
        if (j < off) {
            #pragma unroll
            for (int o = 0; o < 5; o++) red[j][o] += red[j + off][o];
        }
        __syncthreads();
    }
    if (j < 5) out[g * 5 + j] = red[0][j] + b_out[j];
}

// ---------------- launch ----------------

extern "C" void kernel_launch(void* const* d_in, const int* in_sizes, int n_in,
                              void* d_out, int out_size, void* d_ws, size_t ws_size,
                              hipStream_t stream) {
    const float* x        = (const float*)d_in[0];
    const int*   eidx     = (const int*)d_in[1];
    const int*   src      = eidx;
    const int*   dst      = eidx + N_EDGES_C;
    const int*   batch    = (const int*)d_in[2];
    const float* Ws_all   = (const float*)d_in[3];
    const float* bs       = (const float*)d_in[4];
    const float* gammas   = (const float*)d_in[5];
    const float* betas    = (const float*)d_in[6];
    const float* run_mean = (const float*)d_in[7];
    const float* run_var  = (const float*)d_in[8];
    const float* W_out    = (const float*)d_in[9];
    const float* b_out    = (const float*)d_in[10];
    float* out = (float*)d_out;

    char* wp = (char*)d_ws;
    auto alloc = [&](size_t bytes) { char* p = wp; wp += (bytes + 255) & ~(size_t)255; return p; };
    _Float16* yA      = (_Float16*)alloc((size_t)(N_NODES_C + 128) * HID * 2);  // dummy row zeroed by k_gemm0
    _Float16* yB      = (_Float16*)alloc((size_t)(N_NODES_C + 128) * HID * 2);  // dummy row zeroed by k_twhist
    int*      ebuf    = (int*)yA;                 // alias: packed edges, dead before k_gemm0 writes yA
    _Float16* WT      = (_Float16*)alloc((size_t)4 * HID * HID * 2);
    int*      csr_src = (int*)alloc((size_t)(N_EDGES_C + 16) * 4);  // +16 pad for 16-wide chain overread
    int*      offs    = (int*)alloc((size_t)(N_NODES_C + 1) * 4);
    float*    norm    = (float*)alloc((size_t)N_NODES_C * 4);
    // zero-init group: psum | pcount | bcount | relcur contiguous -> ONE memset
    char*     zbeg    = wp;
    float*    psum    = (float*)alloc((size_t)N_GRAPHS_C * HID * 4);
    int*      pcount  = (int*)alloc((size_t)N_GRAPHS_C * 4);
    int*      bcount  = (int*)alloc((NBUCK + 1) * 4);
    int*      relcur  = (int*)alloc((NBUCK + 1) * 4);
    size_t    zlen    = (size_t)(wp - zbeg);

    hipMemsetAsync(zbeg, 0, zlen, stream);

    const int PB = (N_EDGES_C + PART_TILE - 1) / PART_TILE;  // 391
    k_twhist<<<PB, 256, 0, stream>>>(Ws_all, WT, dst, bcount, yB + (size_t)N_NODES_C * HID);
    kb_part <<<PB, 256, 0, stream>>>(src, dst, bcount, relcur, ebuf);
    kb_fill <<<NBUCK, 256, 0, stream>>>(ebuf, bcount, csr_src, offs, norm);

    const int GB = (N_NODES_C + 127) / 128;   // 782
    const int FB = N_NODES_C / 32;            // 3125
    k_gemm0<<<GB, 256, 0, stream>>>(x, WT, norm, yA, N_NODES_C);

    // F1: agg(0) + gemm(1): yA -> yB
    k_fused<false><<<FB, 512, 0, stream>>>((const __half*)yA, yB, WT + 1 * 16384, offs, csr_src, norm,
                                           bs + 0 * HID, run_mean + 0 * HID, gammas + 0 * HID,
                                           run_var + 0 * HID, betas + 0 * HID, nullptr, nullptr, nullptr);
    // F2: agg(1) + gemm(2): yB -> yA
    k_fused<false><<<FB, 512, 0, stream>>>((const __half*)yB, yA, WT + 2 * 16384, offs, csr_src, norm,
                                           bs + 1 * HID, run_mean + 1 * HID, gammas + 1 * HID,
                                           run_var + 1 * HID, betas + 1 * HID, nullptr, nullptr, nullptr);
    // F3: agg(2) + gemm(3): yA -> yB
    k_fused<false><<<FB, 512, 0, stream>>>((const __half*)yA, yB, WT + 3 * 16384, offs, csr_src, norm,
                                           bs + 2 * HID, run_mean + 2 * HID, gammas + 2 * HID,
                                           run_var + 2 * HID, betas + 2 * HID, nullptr, nullptr, nullptr);
    // F4: agg(3) + pool: yB -> psum/pcount
    k_fused<true><<<FB, 512, 0, stream>>>((const __half*)yB, nullptr, nullptr, offs, csr_src, norm,
                                          bs + 3 * HID, run_mean + 3 * HID, gammas + 3 * HID,
                                          run_var + 3 * HID, betas + 3 * HID, batch, psum, pcount);

    k_final<<<N_GRAPHS_C, 128, 0, stream>>>(psum, pcount, W_out, b_out, out);
}